// Round 1
// 813.892 us; speedup vs baseline: 1.4246x; 1.4246x over previous
//
#include <hip/hip_runtime.h>

typedef unsigned short u16;
typedef unsigned int   u32;
typedef __attribute__((ext_vector_type(8))) __bf16 bf16x8;
typedef __attribute__((ext_vector_type(4))) float  f32x4;

#define MREL  8
#define DDIM  256
#define TROWS 32

// ws block layout: each block = 512 u16 = 1KB (one B-fragment set: 64 lanes x 8 bf16)
#define WPHI_B 1024
#define WB_B   2048
#define WC_B   2112
#define NBLK   2496

__device__ __forceinline__ u16 f2bf(float x) {
  u32 u = __float_as_uint(x);
  u += 0x7fffu + ((u >> 16) & 1u);   // RNE
  return (u16)(u >> 16);
}
__device__ __forceinline__ float bf2f(u16 x) {
  return __uint_as_float((u32)x << 16);
}

union U16x8 { u16 u[8]; uint4 q; bf16x8 v; };

// chunk slot inside a 512-u16 ks-group; q=col-quad(0..3), lr=row(0..15), ks=k-slab
#define SLOT(q, lr, ks) ((q)*16 + ((((lr) ^ (ks)) ^ ((q) << 1)) & 15))

#define MFMA16 __builtin_amdgcn_mfma_f32_16x16x32_bf16

// barrier that does NOT drain vmcnt: keeps global prefetch loads in flight
#define BARRIER() do { \
  asm volatile("s_waitcnt lgkmcnt(0)" ::: "memory"); \
  __builtin_amdgcn_s_barrier(); \
  asm volatile("" ::: "memory"); \
} while (0)

// ---------------------------------------------------------------------------
// Prologue: swizzle all weights into bf16 MFMA B-fragment order. (unchanged)
// ---------------------------------------------------------------------------
__global__ __launch_bounds__(256) void swizzle_kernel(
    const float* __restrict__ Wmax, const float* __restrict__ Wphi,
    const float* __restrict__ Wb,   const float* __restrict__ Wc,
    u16* __restrict__ ws)
{
  int sb   = blockIdx.x * 4 + (threadIdx.x >> 6);
  int lane = threadIdx.x & 63;
  int quad = lane >> 4, c16 = lane & 15;
  U16x8 o;
  if (sb < WB_B) {                       // Wmax or Wphi
    const float* W = (sb < WPHI_B) ? Wmax : Wphi;
    int b = sb & 1023;
    int m = b >> 7, r = b & 127;
    int ct = r >> 3, ks = r & 7;
    const float* src = W + ((size_t)m * DDIM + (size_t)(ks * 32 + quad * 8)) * DDIM
                         + ct * 16 + c16;
    #pragma unroll
    for (int j = 0; j < 8; ++j) o.u[j] = f2bf(src[j * DDIM]);
  } else if (sb < WC_B) {                // Wb, zero-padded to 16 cols
    int ksg = sb - WB_B;
    int kbase = ksg * 32 + quad * 8;
    if (c16 < 8) {
      #pragma unroll
      for (int j = 0; j < 8; ++j) o.u[j] = f2bf(Wb[(size_t)(kbase + j) * 8 + c16]);
    } else {
      o.q = make_uint4(0, 0, 0, 0);
    }
  } else {                               // Wc
    int r = sb - WC_B;
    int ct = r / 24, ks = r % 24;
    const float* src = Wc + (size_t)(ks * 32 + quad * 8) * DDIM + ct * 16 + c16;
    #pragma unroll
    for (int j = 0; j < 8; ++j) o.u[j] = f2bf(src[j * DDIM]);
  }
  *(uint4*)(ws + (size_t)sb * 512 + lane * 8) = o.q;
}

// ---------------------------------------------------------------------------
// Fused main kernel, v2: 32 nodes/block, 8 waves (512 thr); wave w owns output
// cols [w*32, w*32+32).  All 8 relation tiles persist in LDS (8 x 16KB); one
// barrier per relation (lgkmcnt-only, vmcnt prefetch survives).  z_sum is
// computed from the persistent tiles (no second HBM pass).  Combine pieces
// alias dead tiles 0..2 and run back-to-back after a single barrier.
// A-frag: lane l holds A[row=l&15][k=(l>>4)*8+j].  C/D: row=(l>>4)*4+r, col=l&15.
// ---------------------------------------------------------------------------
__global__ __launch_bounds__(512, 2) void fused_kernel(
    const float* __restrict__ zs,   const float* __restrict__ bb,
    const float* __restrict__ bmax, const float* __restrict__ bphi,
    const float* __restrict__ bc,   const float* __restrict__ gma,
    const float* __restrict__ bta,  const u16* __restrict__ ws,
    float* __restrict__ out, int N)
{
  const int tid  = threadIdx.x;
  const int lane = tid & 63;
  const int w    = tid >> 6;          // 0..7
  const int quad = lane >> 4;
  const int c16  = lane & 15;
  const int n0   = blockIdx.x * TROWS;
  const int st_row = tid >> 4;        // 0..31 (staging + zsum row)
  const int t15    = tid & 15;

  __shared__ __align__(16) u16 s_tile[MREL * 8192];   // 8 x 16KB = 128KB
  __shared__ float s_lpart[8][TROWS][8];              // gate-logit partials
  __shared__ float s_gate[TROWS][8];
  __shared__ float s_ln1[TROWS][8];
  __shared__ float s_ln2[TROWS][8];
  __shared__ float s_mrs[TROWS][2];

  const f32x4 vz = {0.f, 0.f, 0.f, 0.f};
  f32x4 zmx[2][2], s1v[2][2], s2v[2][2];
  #pragma unroll
  for (int rt = 0; rt < 2; ++rt)
    #pragma unroll
    for (int ct = 0; ct < 2; ++ct) {
      zmx[rt][ct] = (f32x4){-3e38f, -3e38f, -3e38f, -3e38f};
      s1v[rt][ct] = vz; s2v[rt][ct] = vz;
    }
  f32x4 lf0 = vz, lf1 = vz;

  const int g_row = n0 + st_row;
  const int st_lr = st_row & 15, st_rt = st_row >> 4;
  const float* zbase = zs + (size_t)g_row * DDIM + t15 * 4;

  float4 Fa[4], Fb[4];
  auto issue = [&](int m, float4* F) {
    if (g_row < N) {
      const float* p = zbase + (size_t)m * N * DDIM;
      #pragma unroll
      for (int k = 0; k < 4; ++k) F[k] = *(const float4*)(p + k * 64);
    } else {
      #pragma unroll
      for (int k = 0; k < 4; ++k) F[k] = make_float4(0.f, 0.f, 0.f, 0.f);
    }
  };
  auto wtile = [&](int m, const float4* F) {
    u16* tile = s_tile + m * 8192;
    #pragma unroll
    for (int k = 0; k < 4; ++k) {
      int c0 = k * 64 + t15 * 4;
      int ks = c0 >> 5, q = (c0 >> 3) & 3, j = c0 & 7;
      u32 lo = (u32)f2bf(F[k].x) | ((u32)f2bf(F[k].y) << 16);
      u32 hi = (u32)f2bf(F[k].z) | ((u32)f2bf(F[k].w) << 16);
      *(uint2*)(tile + (st_rt * 8 + ks) * 512 + SLOT(q, st_lr, ks) * 8 + j) =
          make_uint2(lo, hi);
    }
  };

  auto compute = [&](int m) {
    const u16* tile = s_tile + m * 8192;
    // bias preloads: issued early, consumed after the MFMA loops
    float bm0 = bmax[m * DDIM + (w * 2 + 0) * 16 + c16];
    float bm1 = bmax[m * DDIM + (w * 2 + 1) * 16 + c16];
    float bp0 = bphi[m * DDIM + (w * 2 + 0) * 16 + c16];
    float bp1 = bphi[m * DDIM + (w * 2 + 1) * 16 + c16];
    // ---- gate logits: this wave handles k-slab ks == w ----
    {
      U16x8 bg, a0, a1;
      bg.q = *(const uint4*)(ws + (size_t)(WB_B + m * 8 + w) * 512 + lane * 8);
      int so = SLOT(quad, c16, w) * 8;
      a0.q = *(const uint4*)(tile + w * 512 + so);
      a1.q = *(const uint4*)(tile + (8 + w) * 512 + so);
      lf0 = MFMA16(a0.v, bg.v, lf0, 0, 0, 0);
      lf1 = MFMA16(a1.v, bg.v, lf1, 0, 0, 0);
    }
    f32x4 pa[2][2];
    // ---- sel 0: Wmax ----
    #pragma unroll
    for (int rt = 0; rt < 2; ++rt)
      #pragma unroll
      for (int ct = 0; ct < 2; ++ct) pa[rt][ct] = vz;
    {
      uint4 B[8][2];                      // preload all B-frags (independent L2 loads)
      #pragma unroll
      for (int ks = 0; ks < 8; ++ks) {
        B[ks][0] = *(const uint4*)(ws + (size_t)(m * 128 + (w * 2 + 0) * 8 + ks) * 512 + lane * 8);
        B[ks][1] = *(const uint4*)(ws + (size_t)(m * 128 + (w * 2 + 1) * 8 + ks) * 512 + lane * 8);
      }
      #pragma unroll
      for (int ks = 0; ks < 8; ++ks) {
        U16x8 a0, a1, b0, b1;
        int so = SLOT(quad, c16, ks) * 8;
        a0.q = *(const uint4*)(tile + ks * 512 + so);
        a1.q = *(const uint4*)(tile + (8 + ks) * 512 + so);
        b0.q = B[ks][0]; b1.q = B[ks][1];
        pa[0][0] = MFMA16(a0.v, b0.v, pa[0][0], 0, 0, 0);
        pa[0][1] = MFMA16(a0.v, b1.v, pa[0][1], 0, 0, 0);
        pa[1][0] = MFMA16(a1.v, b0.v, pa[1][0], 0, 0, 0);
        pa[1][1] = MFMA16(a1.v, b1.v, pa[1][1], 0, 0, 0);
      }
      #pragma unroll
      for (int rt = 0; rt < 2; ++rt)
        #pragma unroll
        for (int r = 0; r < 4; ++r) {
          zmx[rt][0][r] = fmaxf(zmx[rt][0][r], pa[rt][0][r] + bm0);
          zmx[rt][1][r] = fmaxf(zmx[rt][1][r], pa[rt][1][r] + bm1);
        }
    }
    // ---- sel 1: Wphi ----
    #pragma unroll
    for (int rt = 0; rt < 2; ++rt)
      #pragma unroll
      for (int ct = 0; ct < 2; ++ct) pa[rt][ct] = vz;
    {
      uint4 B[8][2];
      #pragma unroll
      for (int ks = 0; ks < 8; ++ks) {
        B[ks][0] = *(const uint4*)(ws + (size_t)(WPHI_B + m * 128 + (w * 2 + 0) * 8 + ks) * 512 + lane * 8);
        B[ks][1] = *(const uint4*)(ws + (size_t)(WPHI_B + m * 128 + (w * 2 + 1) * 8 + ks) * 512 + lane * 8);
      }
      #pragma unroll
      for (int ks = 0; ks < 8; ++ks) {
        U16x8 a0, a1, b0, b1;
        int so = SLOT(quad, c16, ks) * 8;
        a0.q = *(const uint4*)(tile + ks * 512 + so);
        a1.q = *(const uint4*)(tile + (8 + ks) * 512 + so);
        b0.q = B[ks][0]; b1.q = B[ks][1];
        pa[0][0] = MFMA16(a0.v, b0.v, pa[0][0], 0, 0, 0);
        pa[0][1] = MFMA16(a0.v, b1.v, pa[0][1], 0, 0, 0);
        pa[1][0] = MFMA16(a1.v, b0.v, pa[1][0], 0, 0, 0);
        pa[1][1] = MFMA16(a1.v, b1.v, pa[1][1], 0, 0, 0);
      }
      #pragma unroll
      for (int rt = 0; rt < 2; ++rt)
        #pragma unroll
        for (int r = 0; r < 4; ++r) {
          float v0 = pa[rt][0][r] + bp0;
          float v1 = pa[rt][1][r] + bp1;
          s1v[rt][0][r] += v0; s2v[rt][0][r] += v0 * v0;
          s1v[rt][1][r] += v1; s2v[rt][1][r] += v1 * v1;
        }
    }
  };

  // ================= relation loop: stage-ahead + persistent tiles ==========
  issue(0, Fa);
  for (int m = 0; m < MREL; m += 2) {
    issue(m + 1, Fb);
    wtile(m, Fa);
    BARRIER();
    compute(m);
    if (m + 2 < MREL) issue(m + 2, Fa);
    wtile(m + 1, Fb);
    BARRIER();
    compute(m + 1);
  }

  // ================= softmax gate ===========================================
  if (c16 < 8) {
    #pragma unroll
    for (int r = 0; r < 4; ++r) {
      s_lpart[w][quad * 4 + r][c16]      = lf0[r];
      s_lpart[w][16 + quad * 4 + r][c16] = lf1[r];
    }
  }
  __syncthreads();
  if (tid < TROWS) {
    float lg[8]; float mx = -1e30f;
    #pragma unroll
    for (int mm = 0; mm < 8; ++mm) {
      float v = bb[mm];
      #pragma unroll
      for (int ww = 0; ww < 8; ++ww) v += s_lpart[ww][tid][mm];
      lg[mm] = v; mx = fmaxf(mx, v);
    }
    float s = 0.f;
    #pragma unroll
    for (int mm = 0; mm < 8; ++mm) { lg[mm] = __expf(lg[mm] - mx); s += lg[mm]; }
    float inv = 1.f / s;
    #pragma unroll
    for (int mm = 0; mm < 8; ++mm) s_gate[tid][mm] = lg[mm] * inv;
  }
  __syncthreads();

  // ================= z_sum from persistent tiles (no HBM re-read) ===========
  float zsum[16];
  #pragma unroll
  for (int i = 0; i < 16; ++i) zsum[i] = 0.f;
  const int z_ks = t15 >> 1;
  const int z_q0 = (t15 & 1) * 2;
  const int z_base = (st_rt * 8 + z_ks) * 512;
  const int z_so0 = z_base + SLOT(z_q0, st_lr, z_ks) * 8;
  const int z_so1 = z_base + SLOT(z_q0 + 1, st_lr, z_ks) * 8;
  #pragma unroll
  for (int m = 0; m < MREL; ++m) {
    float g = s_gate[st_row][m];
    const u16* tile = s_tile + m * 8192;
    U16x8 v0, v1;
    v0.q = *(const uint4*)(tile + z_so0);
    v1.q = *(const uint4*)(tile + z_so1);
    #pragma unroll
    for (int j = 0; j < 8; ++j) {
      zsum[j]     += g * bf2f(v0.u[j]);
      zsum[8 + j] += g * bf2f(v1.u[j]);
    }
  }
  __syncthreads();   // all tile reads done before pieces overwrite tiles 0..2

  // ================= stage combine pieces (alias tiles 0..2) ================
  {
    U16x8 p0, p1;
    #pragma unroll
    for (int j = 0; j < 8; ++j) { p0.u[j] = f2bf(zsum[j]); p1.u[j] = f2bf(zsum[8 + j]); }
    *(uint4*)(s_tile + z_so0) = p0.q;          // piece 0 = z_sum -> tile0 region
    *(uint4*)(s_tile + z_so1) = p1.q;
  }
  #pragma unroll
  for (int ct = 0; ct < 2; ++ct) {             // piece 1 = z_max -> tile1 region
    int col = (w * 2 + ct) * 16 + c16;
    int ks = col >> 5, q = (col >> 3) & 3, j = col & 7;
    #pragma unroll
    for (int rt = 0; rt < 2; ++rt)
      #pragma unroll
      for (int r = 0; r < 4; ++r) {
        int lr = quad * 4 + r;
        s_tile[8192 + (rt * 8 + ks) * 512 + SLOT(q, lr, ks) * 8 + j] = f2bf(zmx[rt][ct][r]);
      }
  }
  #pragma unroll
  for (int ct = 0; ct < 2; ++ct) {             // piece 2 = z_agr -> tile2 region
    int col = (w * 2 + ct) * 16 + c16;
    int ks = col >> 5, q = (col >> 3) & 3, j = col & 7;
    #pragma unroll
    for (int rt = 0; rt < 2; ++rt)
      #pragma unroll
      for (int r = 0; r < 4; ++r) {
        int lr = quad * 4 + r;
        float za = 0.5f * (s1v[rt][ct][r] * s1v[rt][ct][r] - s2v[rt][ct][r]);
        s_tile[16384 + (rt * 8 + ks) * 512 + SLOT(q, lr, ks) * 8 + j] = f2bf(za);
      }
  }
  __syncthreads();

  // ================= combine GEMM: 3 K=256 pieces, no inner barriers ========
  f32x4 oc[2][2];
  #pragma unroll
  for (int rt = 0; rt < 2; ++rt)
    #pragma unroll
    for (int ct = 0; ct < 2; ++ct) oc[rt][ct] = vz;
  #pragma unroll
  for (int p = 0; p < 3; ++p) {
    const u16* pb = s_tile + p * 8192;
    uint4 B[8][2];
    #pragma unroll
    for (int ks = 0; ks < 8; ++ks) {
      B[ks][0] = *(const uint4*)(ws + (size_t)(WC_B + (w * 2 + 0) * 24 + p * 8 + ks) * 512 + lane * 8);
      B[ks][1] = *(const uint4*)(ws + (size_t)(WC_B + (w * 2 + 1) * 24 + p * 8 + ks) * 512 + lane * 8);
    }
    #pragma unroll
    for (int ks = 0; ks < 8; ++ks) {
      U16x8 a0, a1, b0, b1;
      int so = SLOT(quad, c16, ks) * 8;
      a0.q = *(const uint4*)(pb + ks * 512 + so);
      a1.q = *(const uint4*)(pb + (8 + ks) * 512 + so);
      b0.q = B[ks][0]; b1.q = B[ks][1];
      oc[0][0] = MFMA16(a0.v, b0.v, oc[0][0], 0, 0, 0);
      oc[0][1] = MFMA16(a0.v, b1.v, oc[0][1], 0, 0, 0);
      oc[1][0] = MFMA16(a1.v, b0.v, oc[1][0], 0, 0, 0);
      oc[1][1] = MFMA16(a1.v, b1.v, oc[1][1], 0, 0, 0);
    }
  }

  // ================= + bc, LayerNorm (register/shfl), store =================
  #pragma unroll
  for (int ct = 0; ct < 2; ++ct) {
    float bcv = bc[(w * 2 + ct) * 16 + c16];
    #pragma unroll
    for (int rt = 0; rt < 2; ++rt)
      #pragma unroll
      for (int r = 0; r < 4; ++r) oc[rt][ct][r] += bcv;
  }
  float ps[2][4], pss[2][4];
  #pragma unroll
  for (int rt = 0; rt < 2; ++rt)
    #pragma unroll
    for (int r = 0; r < 4; ++r) {
      float a = oc[rt][0][r], b = oc[rt][1][r];
      ps[rt][r]  = a + b;
      pss[rt][r] = a * a + b * b;
    }
  #pragma unroll
  for (int off = 1; off < 16; off <<= 1) {
    #pragma unroll
    for (int rt = 0; rt < 2; ++rt)
      #pragma unroll
      for (int r = 0; r < 4; ++r) {
        ps[rt][r]  += __shfl_xor(ps[rt][r], off);
        pss[rt][r] += __shfl_xor(pss[rt][r], off);
      }
  }
  if (c16 == 0) {
    #pragma unroll
    for (int rt = 0; rt < 2; ++rt)
      #pragma unroll
      for (int r = 0; r < 4; ++r) s_ln1[rt * 16 + quad * 4 + r][w] = ps[rt][r];
  }
  if (c16 == 1) {
    #pragma unroll
    for (int rt = 0; rt < 2; ++rt)
      #pragma unroll
      for (int r = 0; r < 4; ++r) s_ln2[rt * 16 + quad * 4 + r][w] = pss[rt][r];
  }
  __syncthreads();
  if (tid < TROWS) {
    float s = 0.f, ss = 0.f;
    #pragma unroll
    for (int ww = 0; ww < 8; ++ww) { s += s_ln1[tid][ww]; ss += s_ln2[tid][ww]; }
    float mu  = s * (1.0f / 256.0f);
    float var = ss * (1.0f / 256.0f) - mu * mu;
    s_mrs[tid][0] = mu;
    s_mrs[tid][1] = rsqrtf(var + 1e-5f);
  }
  __syncthreads();
  #pragma unroll
  for (int ct = 0; ct < 2; ++ct) {
    int col = (w * 2 + ct) * 16 + c16;
    float g = gma[col], b = bta[col];
    #pragma unroll
    for (int rt = 0; rt < 2; ++rt)
      #pragma unroll
      for (int r = 0; r < 4; ++r) {
        int row = rt * 16 + quad * 4 + r;
        int grow = n0 + row;
        if (grow < N) {
          float mu = s_mrs[row][0], rs = s_mrs[row][1];
          out[(size_t)grow * DDIM + col] = (oc[rt][ct][r] - mu) * rs * g + b;
        }
      }
  }
}

extern "C" void kernel_launch(void* const* d_in, const int* in_sizes, int n_in,
                              void* d_out, int out_size, void* d_ws, size_t ws_size,
                              hipStream_t stream) {
  const float* zs   = (const float*)d_in[0];
  const float* Wb   = (const float*)d_in[1];
  const float* bb   = (const float*)d_in[2];
  const float* Wmax = (const float*)d_in[3];
  const float* bmax = (const float*)d_in[4];
  const float* Wphi = (const float*)d_in[5];
  const float* bphi = (const float*)d_in[6];
  const float* Wc   = (const float*)d_in[7];
  const float* bc   = (const float*)d_in[8];
  const float* gma  = (const float*)d_in[9];
  const float* bta  = (const float*)d_in[10];
  float* out = (float*)d_out;
  u16* ws = (u16*)d_ws;

  int N = in_sizes[0] / (MREL * DDIM);

  swizzle_kernel<<<NBLK / 4, 256, 0, stream>>>(Wmax, Wphi, Wb, Wc, ws);
  int grid = (N + TROWS - 1) / TROWS;
  fused_kernel<<<grid, 512, 0, stream>>>(zs, bb, bmax, bphi, bc, gma, bta, ws, out, N);
}